// Round 10
// baseline (321.966 us; speedup 1.0000x reference)
//
#include <hip/hip_runtime.h>
#include <hip/hip_bf16.h>
#include <cstdint>

typedef __attribute__((ext_vector_type(4))) float f32x4;
typedef __attribute__((ext_vector_type(16))) float f32x16;
typedef __attribute__((ext_vector_type(8))) short bf16x8;
typedef unsigned short u16;

__device__ inline u16 f2b(float f) {
    union { float f; uint32_t u; } c; c.f = f;
    uint32_t r = (c.u + 0x7FFFu + ((c.u >> 16) & 1u)) >> 16;
    return (u16)r;
}

// ---- Kernel 1: cast X f32 -> bf16 bits (vectorized) ----
__global__ void cast_x_kernel(const float4* __restrict__ X, ushort4* __restrict__ Xb, int n4) {
    int i = blockIdx.x * blockDim.x + threadIdx.x;
    int stride = gridDim.x * blockDim.x;
    for (; i < n4; i += stride) {
        float4 v = X[i];
        ushort4 o;
        o.x = f2b(v.x); o.y = f2b(v.y); o.z = f2b(v.z); o.w = f2b(v.w);
        Xb[i] = o;
    }
}

// ---- Kernel 2: FWHT over each 1024-block of W rows, float4-wide, scale 1/32 ----
__global__ void fwht_w_kernel(const float4* __restrict__ W4, ushort4* __restrict__ Wh4) {
    __shared__ float4 s4[2][256];
    const int tid = threadIdx.x;
    const size_t base = (size_t)blockIdx.x * 256;
    float4 v = W4[base + tid];
    v = float4{v.x + v.y, v.x - v.y, v.z + v.w, v.z - v.w};   // h=1
    v = float4{v.x + v.z, v.y + v.w, v.x - v.z, v.y - v.w};   // h=2
    int cur = 0;
    s4[0][tid] = v;
    __syncthreads();
#pragma unroll
    for (int h4 = 1; h4 < 256; h4 <<= 1) {
        float4 a = s4[cur][tid];
        float4 b = s4[cur][tid ^ h4];
        float4 r;
        if (tid & h4) r = float4{b.x - a.x, b.y - a.y, b.z - a.z, b.w - a.w};
        else          r = float4{a.x + b.x, a.y + b.y, a.z + b.z, a.w + b.w};
        cur ^= 1;
        s4[cur][tid] = r;
        __syncthreads();
        v = r;
    }
    ushort4 o;
    o.x = f2b(v.x * 0.03125f); o.y = f2b(v.y * 0.03125f);
    o.z = f2b(v.z * 0.03125f); o.w = f2b(v.w * 0.03125f);
    Wh4[base + tid] = o;
}

// ---- Kernel 3: 256x256-tile 8-wave pipelined bf16 GEMM, C = A * B^T ----
// r7-verified depth-2 schedule, MFMA shape switched 16x16x32 -> 32x32x16
// (2382 vs 2075 TF ceiling; half the MFMA instructions). Per-wave out 128x64 =
// 4 m-frags x 2 n-frags x 4 k-steps; fragment sets F0..F3 and their LDS
// regions/read counts map 1:1 onto the r7 schedule, so all counted waits,
// barriers, staging slots and the WAR/RAW audit carry over verbatim:
//   P0: stage B1(t+1)->nb; issue F2(8);  lgkm(8)  [F0 done]; Q0 -> acc[0..1][*]
//   P1: issue F3(4);                     lgkm(12) [F1 done]; Q1 -> acc[2..3][*]
//   P2: lgkm(4)[F2]+vmcnt(2); bar; stage B0(t+2)->cb; issue F1'(4); Q2
//   P3: lgkm(4)[F3]+vmcnt(2); bar; stage A(t+2)->cb;  issue F0'(8); Q3
// A/B frag: row=lane&31, k=(lane>>5)*8 within 16-k step; swizzled slot
// (2ks+(lane>>5))^(lane&7) — every consecutive-8-lane group hits 8 distinct
// 16B slots (conflict-free, same property as r7's pattern).
// C/D layout (32x32): col=lane&31, row=(reg&3)+8*(reg>>2)+4*(lane>>5).
#define MFMA32(a, b, c) __builtin_amdgcn_mfma_f32_32x32x16_bf16(a, b, c, 0, 0, 0)

__global__ __launch_bounds__(512, 2) void gemm256_kernel(
    const u16* __restrict__ A, const u16* __restrict__ B, float* __restrict__ C,
    int M, int N, int K)
{
    __shared__ u16 lds[2][2][2][8192];   // [buf][op A=0/B=1][half][128*64]

    const int tid  = threadIdx.x;
    const int wid  = tid >> 6;
    const int lane = tid & 63;
    const int wr   = wid >> 2;           // 0..1
    const int wc   = wid & 3;            // 0..3

    const int ntn = N / 256;
    const int nwg = (M / 256) * ntn;
    int bid = blockIdx.x;
    int swz = (nwg % 8 == 0) ? ((bid & 7) * (nwg >> 3) + (bid >> 3)) : bid;
    const int tm = swz / ntn, tn = swz % ntn;
    const size_t rowA0 = (size_t)tm * 256;
    const size_t rowB0 = (size_t)tn * 256;
    const int TSTEPS = K / 64;

    const int stg_row  = wid * 8 + (lane >> 3);
    const int stg_slot = (lane & 7) ^ (stg_row & 7);   // pre-swizzled source slot

    // read-side constants (32x32 frags): row=(lane&31), k-slot=(2ks+hi)^(lane&7)
    const int frow = (lane & 31) * 64;
    const int hi5  = lane >> 5;
    const int s0 = ((0 + hi5) ^ (lane & 7)) * 8;   // ks0
    const int s1 = ((2 + hi5) ^ (lane & 7)) * 8;   // ks1
    const int s2 = ((4 + hi5) ^ (lane & 7)) * 8;   // ks2
    const int s3 = ((6 + hi5) ^ (lane & 7)) * 8;   // ks3

    auto stage = [&](const u16* __restrict__ G, size_t rowbase, u16* ldsHalf, int chunk, int t) {
        int teff = t < TSTEPS ? t : TSTEPS - 1;
        const u16* g = G + (rowbase + (size_t)(chunk * 64 + stg_row)) * (size_t)K
                         + teff * 64 + stg_slot * 8;
        u16* l = ldsHalf + chunk * 4096 + wid * 512;   // wave-uniform base; HW adds lane*16B
        __builtin_amdgcn_global_load_lds((const __attribute__((address_space(1))) void*)g,
                                         (__attribute__((address_space(3))) void*)l, 16, 0, 0);
    };

    f32x16 acc[4][2];
#pragma unroll
    for (int i = 0; i < 4; ++i)
#pragma unroll
        for (int j = 0; j < 2; ++j) acc[i][j] = (f32x16)(0.0f);

    // ---- prologue (identical structure to r7) ----
    stage(B, rowB0,       &lds[0][1][0][0], 0, 0);   // B0(0)
    stage(B, rowB0,       &lds[0][1][0][0], 1, 0);
    stage(A, rowA0,       &lds[0][0][0][0], 0, 0);   // A(0)
    stage(A, rowA0,       &lds[0][0][0][0], 1, 0);
    stage(A, rowA0 + 128, &lds[0][0][1][0], 0, 0);
    stage(A, rowA0 + 128, &lds[0][0][1][0], 1, 0);
    stage(B, rowB0 + 128, &lds[0][1][1][0], 0, 0);   // B1(0)
    stage(B, rowB0 + 128, &lds[0][1][1][0], 1, 0);
    stage(B, rowB0,       &lds[1][1][0][0], 0, 1);   // B0(1)
    stage(B, rowB0,       &lds[1][1][0][0], 1, 1);
    asm volatile("s_waitcnt vmcnt(2)" ::: "memory");  // ALL of tile0 landed (incl. B1(0))
    __builtin_amdgcn_s_barrier();
    stage(A, rowA0,       &lds[1][0][0][0], 0, 1);   // A(1)
    stage(A, rowA0,       &lds[1][0][0][0], 1, 1);
    stage(A, rowA0 + 128, &lds[1][0][1][0], 0, 1);
    stage(A, rowA0 + 128, &lds[1][0][1][0], 1, 1);
    // vmem FIFO entering loop: [B0(1) 2][A(1) 4] = 6 outstanding.

    // fragment arrays: [mf*2+ks] / [nf*2+ks]
    bf16x8 a0[4], b0[4], a1[4], cF[4], dF[4], eF[4];
    {
        const u16* Ahalf = &lds[0][0][wr][0];
        const u16* Bbase = &lds[0][1][wc >> 1][(wc & 1) * 4096];
        a0[0] = *(const bf16x8*)&Ahalf[0 * 2048 + frow + s0];
        a0[1] = *(const bf16x8*)&Ahalf[0 * 2048 + frow + s1];
        a0[2] = *(const bf16x8*)&Ahalf[1 * 2048 + frow + s0];
        a0[3] = *(const bf16x8*)&Ahalf[1 * 2048 + frow + s1];
        b0[0] = *(const bf16x8*)&Bbase[0 * 2048 + frow + s0];
        b0[1] = *(const bf16x8*)&Bbase[0 * 2048 + frow + s1];
        b0[2] = *(const bf16x8*)&Bbase[1 * 2048 + frow + s0];
        b0[3] = *(const bf16x8*)&Bbase[1 * 2048 + frow + s1];
        a1[0] = *(const bf16x8*)&Ahalf[2 * 2048 + frow + s0];
        a1[1] = *(const bf16x8*)&Ahalf[2 * 2048 + frow + s1];
        a1[2] = *(const bf16x8*)&Ahalf[3 * 2048 + frow + s0];
        a1[3] = *(const bf16x8*)&Ahalf[3 * 2048 + frow + s1];
    }

    for (int t = 0; t < TSTEPS; ++t) {
        const int cb = t & 1, nb = cb ^ 1;
        const u16* Ahalf  = &lds[cb][0][wr][0];
        const u16* Bbase  = &lds[cb][1][wc >> 1][(wc & 1) * 4096];
        const u16* AhalfN = &lds[nb][0][wr][0];
        const u16* BbaseN = &lds[nb][1][wc >> 1][(wc & 1) * 4096];

        // ===== P0: stage B1(t+1)->nb; issue F2 (cF,dF: ks2,3); lgkm(8) [F0 done]; Q0 =====
        stage(B, rowB0 + 128, &lds[nb][1][1][0], 0, t + 1);
        stage(B, rowB0 + 128, &lds[nb][1][1][0], 1, t + 1);
        cF[0] = *(const bf16x8*)&Ahalf[0 * 2048 + frow + s2];
        cF[1] = *(const bf16x8*)&Ahalf[0 * 2048 + frow + s3];
        cF[2] = *(const bf16x8*)&Ahalf[1 * 2048 + frow + s2];
        cF[3] = *(const bf16x8*)&Ahalf[1 * 2048 + frow + s3];
        dF[0] = *(const bf16x8*)&Bbase[0 * 2048 + frow + s2];
        dF[1] = *(const bf16x8*)&Bbase[0 * 2048 + frow + s3];
        dF[2] = *(const bf16x8*)&Bbase[1 * 2048 + frow + s2];
        dF[3] = *(const bf16x8*)&Bbase[1 * 2048 + frow + s3];
        asm volatile("s_waitcnt lgkmcnt(8)" ::: "memory");
        __builtin_amdgcn_sched_barrier(0);
        __builtin_amdgcn_s_setprio(1);
#pragma unroll
        for (int mf = 0; mf < 2; ++mf)
#pragma unroll
            for (int nf = 0; nf < 2; ++nf)
#pragma unroll
                for (int ks = 0; ks < 2; ++ks)
                    acc[mf][nf] = MFMA32(a0[mf * 2 + ks], b0[nf * 2 + ks], acc[mf][nf]);
        __builtin_amdgcn_s_setprio(0);

        // ===== P1: issue F3 (eF: mf2,3 ks2,3); lgkm(12) pacing [F1 done]; Q1 =====
        eF[0] = *(const bf16x8*)&Ahalf[2 * 2048 + frow + s2];
        eF[1] = *(const bf16x8*)&Ahalf[2 * 2048 + frow + s3];
        eF[2] = *(const bf16x8*)&Ahalf[3 * 2048 + frow + s2];
        eF[3] = *(const bf16x8*)&Ahalf[3 * 2048 + frow + s3];
        asm volatile("s_waitcnt lgkmcnt(12)" ::: "memory");
        __builtin_amdgcn_sched_barrier(0);
        __builtin_amdgcn_s_setprio(1);
#pragma unroll
        for (int mf = 0; mf < 2; ++mf)
#pragma unroll
            for (int nf = 0; nf < 2; ++nf)
#pragma unroll
                for (int ks = 0; ks < 2; ++ks)
                    acc[2 + mf][nf] = MFMA32(a1[mf * 2 + ks], b0[nf * 2 + ks], acc[2 + mf][nf]);
        __builtin_amdgcn_s_setprio(0);

        // ===== P2: lgkm(4) [F2 done]; vmcnt(2) [B0,A(t+1) landed]; bar;
        //          stage B0(t+2)->cb; issue F1' (a1: next tile); Q2 =====
        asm volatile("s_waitcnt lgkmcnt(4)" ::: "memory");
        asm volatile("s_waitcnt vmcnt(2)" ::: "memory");
        __builtin_amdgcn_sched_barrier(0);
        __builtin_amdgcn_s_barrier();
        stage(B, rowB0, &lds[cb][1][0][0], 0, t + 2);
        stage(B, rowB0, &lds[cb][1][0][0], 1, t + 2);
        a1[0] = *(const bf16x8*)&AhalfN[2 * 2048 + frow + s0];
        a1[1] = *(const bf16x8*)&AhalfN[2 * 2048 + frow + s1];
        a1[2] = *(const bf16x8*)&AhalfN[3 * 2048 + frow + s0];
        a1[3] = *(const bf16x8*)&AhalfN[3 * 2048 + frow + s1];
        __builtin_amdgcn_s_setprio(1);
#pragma unroll
        for (int mf = 0; mf < 2; ++mf)
#pragma unroll
            for (int nf = 0; nf < 2; ++nf)
#pragma unroll
                for (int ks = 0; ks < 2; ++ks)
                    acc[mf][nf] = MFMA32(cF[mf * 2 + ks], dF[nf * 2 + ks], acc[mf][nf]);
        __builtin_amdgcn_s_setprio(0);

        // ===== P3: lgkm(4) [F3 done]; vmcnt(2) [B1(t+1) landed]; bar;
        //          stage A(t+2)->cb; issue F0' (a0,b0: next tile); Q3 =====
        asm volatile("s_waitcnt lgkmcnt(4)" ::: "memory");
        asm volatile("s_waitcnt vmcnt(2)" ::: "memory");
        __builtin_amdgcn_sched_barrier(0);
        __builtin_amdgcn_s_barrier();
        stage(A, rowA0,       &lds[cb][0][0][0], 0, t + 2);
        stage(A, rowA0,       &lds[cb][0][0][0], 1, t + 2);
        stage(A, rowA0 + 128, &lds[cb][0][1][0], 0, t + 2);
        stage(A, rowA0 + 128, &lds[cb][0][1][0], 1, t + 2);
        a0[0] = *(const bf16x8*)&AhalfN[0 * 2048 + frow + s0];
        a0[1] = *(const bf16x8*)&AhalfN[0 * 2048 + frow + s1];
        a0[2] = *(const bf16x8*)&AhalfN[1 * 2048 + frow + s0];
        a0[3] = *(const bf16x8*)&AhalfN[1 * 2048 + frow + s1];
        b0[0] = *(const bf16x8*)&BbaseN[0 * 2048 + frow + s0];
        b0[1] = *(const bf16x8*)&BbaseN[0 * 2048 + frow + s1];
        b0[2] = *(const bf16x8*)&BbaseN[1 * 2048 + frow + s0];
        b0[3] = *(const bf16x8*)&BbaseN[1 * 2048 + frow + s1];
        __builtin_amdgcn_s_setprio(1);
#pragma unroll
        for (int mf = 0; mf < 2; ++mf)
#pragma unroll
            for (int nf = 0; nf < 2; ++nf)
#pragma unroll
                for (int ks = 0; ks < 2; ++ks)
                    acc[2 + mf][nf] = MFMA32(eF[mf * 2 + ks], dF[nf * 2 + ks], acc[2 + mf][nf]);
        __builtin_amdgcn_s_setprio(0);
    }

    // ---- epilogue: 32x32 C/D layout: col=lane&31, row=(reg&3)+8*(reg>>2)+4*hi5 ----
#pragma unroll
    for (int mf = 0; mf < 4; ++mf) {
        size_t row0 = rowA0 + wr * 128 + mf * 32 + 4 * hi5;
#pragma unroll
        for (int nf = 0; nf < 2; ++nf) {
            size_t col = rowB0 + wc * 64 + nf * 32 + (lane & 31);
            f32x16 v = acc[mf][nf];
#pragma unroll
            for (int g = 0; g < 4; ++g)
#pragma unroll
                for (int j = 0; j < 4; ++j)
                    C[(row0 + 8 * g + j) * (size_t)N + col] = v[4 * g + j];
        }
    }
}

extern "C" void kernel_launch(void* const* d_in, const int* in_sizes, int n_in,
                              void* d_out, int out_size, void* d_ws, size_t ws_size,
                              hipStream_t stream) {
    const float* X = (const float*)d_in[0];   // (4,2048,4096) f32
    const float* W = (const float*)d_in[1];   // (4096,4096) f32
    float* Out = (float*)d_out;               // (4,2048,4096) f32

    const int K = 4096;
    const int N = in_sizes[1] / K;            // 4096
    const int M = in_sizes[0] / K;            // 8192

    u16* Xb = (u16*)d_ws;                     // M*K bf16 (64 MB)
    u16* Wh = (u16*)d_ws + (size_t)M * K;     // N*K bf16 (32 MB)

    cast_x_kernel<<<2048, 256, 0, stream>>>((const float4*)X, (ushort4*)Xb, (M * K) / 4);
    fwht_w_kernel<<<(size_t)N * K / 1024, 256, 0, stream>>>((const float4*)W, (ushort4*)Wh);

    dim3 grid((M / 256) * (N / 256));
    gemm256_kernel<<<grid, 512, 0, stream>>>(Xb, Wh, Out, M, N, K);
}

// Round 11
// 319.572 us; speedup vs baseline: 1.0075x; 1.0075x over previous
//
#include <hip/hip_runtime.h>
#include <hip/hip_bf16.h>
#include <cstdint>

typedef __attribute__((ext_vector_type(4))) float f32x4;
typedef __attribute__((ext_vector_type(16))) float f32x16;
typedef __attribute__((ext_vector_type(8))) short bf16x8;
typedef unsigned short u16;

__device__ inline u16 f2b(float f) {
    union { float f; uint32_t u; } c; c.f = f;
    uint32_t r = (c.u + 0x7FFFu + ((c.u >> 16) & 1u)) >> 16;
    return (u16)r;
}

// ---- Kernel 1: cast X f32 -> bf16 bits (vectorized) ----
__global__ void cast_x_kernel(const float4* __restrict__ X, ushort4* __restrict__ Xb, int n4) {
    int i = blockIdx.x * blockDim.x + threadIdx.x;
    int stride = gridDim.x * blockDim.x;
    for (; i < n4; i += stride) {
        float4 v = X[i];
        ushort4 o;
        o.x = f2b(v.x); o.y = f2b(v.y); o.z = f2b(v.z); o.w = f2b(v.w);
        Xb[i] = o;
    }
}

// ---- Kernel 2: FWHT over each 1024-block of W rows, float4-wide, scale 1/32 ----
__global__ void fwht_w_kernel(const float4* __restrict__ W4, ushort4* __restrict__ Wh4) {
    __shared__ float4 s4[2][256];
    const int tid = threadIdx.x;
    const size_t base = (size_t)blockIdx.x * 256;
    float4 v = W4[base + tid];
    v = float4{v.x + v.y, v.x - v.y, v.z + v.w, v.z - v.w};   // h=1
    v = float4{v.x + v.z, v.y + v.w, v.x - v.z, v.y - v.w};   // h=2
    int cur = 0;
    s4[0][tid] = v;
    __syncthreads();
#pragma unroll
    for (int h4 = 1; h4 < 256; h4 <<= 1) {
        float4 a = s4[cur][tid];
        float4 b = s4[cur][tid ^ h4];
        float4 r;
        if (tid & h4) r = float4{b.x - a.x, b.y - a.y, b.z - a.z, b.w - a.w};
        else          r = float4{a.x + b.x, a.y + b.y, a.z + b.z, a.w + b.w};
        cur ^= 1;
        s4[cur][tid] = r;
        __syncthreads();
        v = r;
    }
    ushort4 o;
    o.x = f2b(v.x * 0.03125f); o.y = f2b(v.y * 0.03125f);
    o.z = f2b(v.z * 0.03125f); o.w = f2b(v.w * 0.03125f);
    Wh4[base + tid] = o;
}

// ---- Kernel 3: 256x256-tile 8-wave pipelined bf16 GEMM, C = A * B^T ----
// r10 structure (32x32x16 MFMA, depth-2 schedule) with the bank-conflict fix:
// swizzle extended from g(r)=r&7 to g(r)=(r&7)^((r>>3)&3) so rows differing
// by 8 within a 32-row read block map to distinct 16B slots. r10 PMC showed
// lanes {l,l+8,l+16,l+24} (equal row&7) aliased 4-way -> 2.54e7 conflicts.
// Store side: physical slot p at row r holds logical slot p^g(r); staging lane
// writes physical slot lane&7 at row stg_row=wid*8+(lane>>3), so the
// pre-swizzled global source slot = (lane&7)^(lane>>3)^(wid&3).
// Read side: logical slot (2ks+hi5) at row r=lane&31 -> physical
// ((2ks+hi5)^(lane&7)^((lane>>3)&3)). Bijective per row (rule #21: same
// involution both sides). Schedule/waits/barriers/epilogue identical to r10
// (r10 passed correctness; only the slot permutation changes).
#define MFMA32(a, b, c) __builtin_amdgcn_mfma_f32_32x32x16_bf16(a, b, c, 0, 0, 0)

__global__ __launch_bounds__(512, 2) void gemm256_kernel(
    const u16* __restrict__ A, const u16* __restrict__ B, float* __restrict__ C,
    int M, int N, int K)
{
    __shared__ u16 lds[2][2][2][8192];   // [buf][op A=0/B=1][half][128*64]

    const int tid  = threadIdx.x;
    const int wid  = tid >> 6;
    const int lane = tid & 63;
    const int wr   = wid >> 2;           // 0..1
    const int wc   = wid & 3;            // 0..3

    const int ntn = N / 256;
    const int nwg = (M / 256) * ntn;
    int bid = blockIdx.x;
    int swz = (nwg % 8 == 0) ? ((bid & 7) * (nwg >> 3) + (bid >> 3)) : bid;
    const int tm = swz / ntn, tn = swz % ntn;
    const size_t rowA0 = (size_t)tm * 256;
    const size_t rowB0 = (size_t)tn * 256;
    const int TSTEPS = K / 64;

    const int stg_row  = wid * 8 + (lane >> 3);
    const int stg_slot = (lane & 7) ^ (lane >> 3) ^ (wid & 3);   // source slot = (lane&7)^g(stg_row)

    // read-side constants (32x32 frags): row=(lane&31), g(r)=(r&7)^((r>>3)&3)
    const int hi5  = lane >> 5;
    const int gr   = (lane & 7) ^ ((lane >> 3) & 3);
    const int frow = (lane & 31) * 64;
    const int s0 = ((0 + hi5) ^ gr) * 8;   // ks0
    const int s1 = ((2 + hi5) ^ gr) * 8;   // ks1
    const int s2 = ((4 + hi5) ^ gr) * 8;   // ks2
    const int s3 = ((6 + hi5) ^ gr) * 8;   // ks3

    auto stage = [&](const u16* __restrict__ G, size_t rowbase, u16* ldsHalf, int chunk, int t) {
        int teff = t < TSTEPS ? t : TSTEPS - 1;
        const u16* g = G + (rowbase + (size_t)(chunk * 64 + stg_row)) * (size_t)K
                         + teff * 64 + stg_slot * 8;
        u16* l = ldsHalf + chunk * 4096 + wid * 512;   // wave-uniform base; HW adds lane*16B
        __builtin_amdgcn_global_load_lds((const __attribute__((address_space(1))) void*)g,
                                         (__attribute__((address_space(3))) void*)l, 16, 0, 0);
    };

    f32x16 acc[4][2];
#pragma unroll
    for (int i = 0; i < 4; ++i)
#pragma unroll
        for (int j = 0; j < 2; ++j) acc[i][j] = (f32x16)(0.0f);

    // ---- prologue (identical structure to r7/r10) ----
    stage(B, rowB0,       &lds[0][1][0][0], 0, 0);   // B0(0)
    stage(B, rowB0,       &lds[0][1][0][0], 1, 0);
    stage(A, rowA0,       &lds[0][0][0][0], 0, 0);   // A(0)
    stage(A, rowA0,       &lds[0][0][0][0], 1, 0);
    stage(A, rowA0 + 128, &lds[0][0][1][0], 0, 0);
    stage(A, rowA0 + 128, &lds[0][0][1][0], 1, 0);
    stage(B, rowB0 + 128, &lds[0][1][1][0], 0, 0);   // B1(0)
    stage(B, rowB0 + 128, &lds[0][1][1][0], 1, 0);
    stage(B, rowB0,       &lds[1][1][0][0], 0, 1);   // B0(1)
    stage(B, rowB0,       &lds[1][1][0][0], 1, 1);
    asm volatile("s_waitcnt vmcnt(2)" ::: "memory");  // ALL of tile0 landed (incl. B1(0))
    __builtin_amdgcn_s_barrier();
    stage(A, rowA0,       &lds[1][0][0][0], 0, 1);   // A(1)
    stage(A, rowA0,       &lds[1][0][0][0], 1, 1);
    stage(A, rowA0 + 128, &lds[1][0][1][0], 0, 1);
    stage(A, rowA0 + 128, &lds[1][0][1][0], 1, 1);
    // vmem FIFO entering loop: [B0(1) 2][A(1) 4] = 6 outstanding.

    // fragment arrays: [mf*2+ks] / [nf*2+ks]
    bf16x8 a0[4], b0[4], a1[4], cF[4], dF[4], eF[4];
    {
        const u16* Ahalf = &lds[0][0][wr][0];
        const u16* Bbase = &lds[0][1][wc >> 1][(wc & 1) * 4096];
        a0[0] = *(const bf16x8*)&Ahalf[0 * 2048 + frow + s0];
        a0[1] = *(const bf16x8*)&Ahalf[0 * 2048 + frow + s1];
        a0[2] = *(const bf16x8*)&Ahalf[1 * 2048 + frow + s0];
        a0[3] = *(const bf16x8*)&Ahalf[1 * 2048 + frow + s1];
        b0[0] = *(const bf16x8*)&Bbase[0 * 2048 + frow + s0];
        b0[1] = *(const bf16x8*)&Bbase[0 * 2048 + frow + s1];
        b0[2] = *(const bf16x8*)&Bbase[1 * 2048 + frow + s0];
        b0[3] = *(const bf16x8*)&Bbase[1 * 2048 + frow + s1];
        a1[0] = *(const bf16x8*)&Ahalf[2 * 2048 + frow + s0];
        a1[1] = *(const bf16x8*)&Ahalf[2 * 2048 + frow + s1];
        a1[2] = *(const bf16x8*)&Ahalf[3 * 2048 + frow + s0];
        a1[3] = *(const bf16x8*)&Ahalf[3 * 2048 + frow + s1];
    }

    for (int t = 0; t < TSTEPS; ++t) {
        const int cb = t & 1, nb = cb ^ 1;
        const u16* Ahalf  = &lds[cb][0][wr][0];
        const u16* Bbase  = &lds[cb][1][wc >> 1][(wc & 1) * 4096];
        const u16* AhalfN = &lds[nb][0][wr][0];
        const u16* BbaseN = &lds[nb][1][wc >> 1][(wc & 1) * 4096];

        // ===== P0: stage B1(t+1)->nb; issue F2 (cF,dF: ks2,3); lgkm(8) [F0 done]; Q0 =====
        stage(B, rowB0 + 128, &lds[nb][1][1][0], 0, t + 1);
        stage(B, rowB0 + 128, &lds[nb][1][1][0], 1, t + 1);
        cF[0] = *(const bf16x8*)&Ahalf[0 * 2048 + frow + s2];
        cF[1] = *(const bf16x8*)&Ahalf[0 * 2048 + frow + s3];
        cF[2] = *(const bf16x8*)&Ahalf[1 * 2048 + frow + s2];
        cF[3] = *(const bf16x8*)&Ahalf[1 * 2048 + frow + s3];
        dF[0] = *(const bf16x8*)&Bbase[0 * 2048 + frow + s2];
        dF[1] = *(const bf16x8*)&Bbase[0 * 2048 + frow + s3];
        dF[2] = *(const bf16x8*)&Bbase[1 * 2048 + frow + s2];
        dF[3] = *(const bf16x8*)&Bbase[1 * 2048 + frow + s3];
        asm volatile("s_waitcnt lgkmcnt(8)" ::: "memory");
        __builtin_amdgcn_sched_barrier(0);
        __builtin_amdgcn_s_setprio(1);
#pragma unroll
        for (int mf = 0; mf < 2; ++mf)
#pragma unroll
            for (int nf = 0; nf < 2; ++nf)
#pragma unroll
                for (int ks = 0; ks < 2; ++ks)
                    acc[mf][nf] = MFMA32(a0[mf * 2 + ks], b0[nf * 2 + ks], acc[mf][nf]);
        __builtin_amdgcn_s_setprio(0);

        // ===== P1: issue F3 (eF: mf2,3 ks2,3); lgkm(12) pacing [F1 done]; Q1 =====
        eF[0] = *(const bf16x8*)&Ahalf[2 * 2048 + frow + s2];
        eF[1] = *(const bf16x8*)&Ahalf[2 * 2048 + frow + s3];
        eF[2] = *(const bf16x8*)&Ahalf[3 * 2048 + frow + s2];
        eF[3] = *(const bf16x8*)&Ahalf[3 * 2048 + frow + s3];
        asm volatile("s_waitcnt lgkmcnt(12)" ::: "memory");
        __builtin_amdgcn_sched_barrier(0);
        __builtin_amdgcn_s_setprio(1);
#pragma unroll
        for (int mf = 0; mf < 2; ++mf)
#pragma unroll
            for (int nf = 0; nf < 2; ++nf)
#pragma unroll
                for (int ks = 0; ks < 2; ++ks)
                    acc[2 + mf][nf] = MFMA32(a1[mf * 2 + ks], b0[nf * 2 + ks], acc[2 + mf][nf]);
        __builtin_amdgcn_s_setprio(0);

        // ===== P2: lgkm(4) [F2 done]; vmcnt(2) [B0,A(t+1) landed]; bar;
        //          stage B0(t+2)->cb; issue F1' (a1: next tile); Q2 =====
        asm volatile("s_waitcnt lgkmcnt(4)" ::: "memory");
        asm volatile("s_waitcnt vmcnt(2)" ::: "memory");
        __builtin_amdgcn_sched_barrier(0);
        __builtin_amdgcn_s_barrier();
        stage(B, rowB0, &lds[cb][1][0][0], 0, t + 2);
        stage(B, rowB0, &lds[cb][1][0][0], 1, t + 2);
        a1[0] = *(const bf16x8*)&AhalfN[2 * 2048 + frow + s0];
        a1[1] = *(const bf16x8*)&AhalfN[2 * 2048 + frow + s1];
        a1[2] = *(const bf16x8*)&AhalfN[3 * 2048 + frow + s0];
        a1[3] = *(const bf16x8*)&AhalfN[3 * 2048 + frow + s1];
        __builtin_amdgcn_s_setprio(1);
#pragma unroll
        for (int mf = 0; mf < 2; ++mf)
#pragma unroll
            for (int nf = 0; nf < 2; ++nf)
#pragma unroll
                for (int ks = 0; ks < 2; ++ks)
                    acc[mf][nf] = MFMA32(cF[mf * 2 + ks], dF[nf * 2 + ks], acc[mf][nf]);
        __builtin_amdgcn_s_setprio(0);

        // ===== P3: lgkm(4) [F3 done]; vmcnt(2) [B1(t+1) landed]; bar;
        //          stage A(t+2)->cb; issue F0' (a0,b0: next tile); Q3 =====
        asm volatile("s_waitcnt lgkmcnt(4)" ::: "memory");
        asm volatile("s_waitcnt vmcnt(2)" ::: "memory");
        __builtin_amdgcn_sched_barrier(0);
        __builtin_amdgcn_s_barrier();
        stage(A, rowA0,       &lds[cb][0][0][0], 0, t + 2);
        stage(A, rowA0,       &lds[cb][0][0][0], 1, t + 2);
        stage(A, rowA0 + 128, &lds[cb][0][1][0], 0, t + 2);
        stage(A, rowA0 + 128, &lds[cb][0][1][0], 1, t + 2);
        a0[0] = *(const bf16x8*)&AhalfN[0 * 2048 + frow + s0];
        a0[1] = *(const bf16x8*)&AhalfN[0 * 2048 + frow + s1];
        a0[2] = *(const bf16x8*)&AhalfN[1 * 2048 + frow + s0];
        a0[3] = *(const bf16x8*)&AhalfN[1 * 2048 + frow + s1];
        b0[0] = *(const bf16x8*)&BbaseN[0 * 2048 + frow + s0];
        b0[1] = *(const bf16x8*)&BbaseN[0 * 2048 + frow + s1];
        b0[2] = *(const bf16x8*)&BbaseN[1 * 2048 + frow + s0];
        b0[3] = *(const bf16x8*)&BbaseN[1 * 2048 + frow + s1];
        __builtin_amdgcn_s_setprio(1);
#pragma unroll
        for (int mf = 0; mf < 2; ++mf)
#pragma unroll
            for (int nf = 0; nf < 2; ++nf)
#pragma unroll
                for (int ks = 0; ks < 2; ++ks)
                    acc[2 + mf][nf] = MFMA32(eF[mf * 2 + ks], dF[nf * 2 + ks], acc[2 + mf][nf]);
        __builtin_amdgcn_s_setprio(0);
    }

    // ---- epilogue: 32x32 C/D layout: col=lane&31, row=(reg&3)+8*(reg>>2)+4*hi5 ----
#pragma unroll
    for (int mf = 0; mf < 4; ++mf) {
        size_t row0 = rowA0 + wr * 128 + mf * 32 + 4 * hi5;
#pragma unroll
        for (int nf = 0; nf < 2; ++nf) {
            size_t col = rowB0 + wc * 64 + nf * 32 + (lane & 31);
            f32x16 v = acc[mf][nf];
#pragma unroll
            for (int g = 0; g < 4; ++g)
#pragma unroll
                for (int j = 0; j < 4; ++j)
                    C[(row0 + 8 * g + j) * (size_t)N + col] = v[4 * g + j];
        }
    }
}

extern "C" void kernel_launch(void* const* d_in, const int* in_sizes, int n_in,
                              void* d_out, int out_size, void* d_ws, size_t ws_size,
                              hipStream_t stream) {
    const float* X = (const float*)d_in[0];   // (4,2048,4096) f32
    const float* W = (const float*)d_in[1];   // (4096,4096) f32
    float* Out = (float*)d_out;               // (4,2048,4096) f32

    const int K = 4096;
    const int N = in_sizes[1] / K;            // 4096
    const int M = in_sizes[0] / K;            // 8192

    u16* Xb = (u16*)d_ws;                     // M*K bf16 (64 MB)
    u16* Wh = (u16*)d_ws + (size_t)M * K;     // N*K bf16 (32 MB)

    cast_x_kernel<<<2048, 256, 0, stream>>>((const float4*)X, (ushort4*)Xb, (M * K) / 4);
    fwht_w_kernel<<<(size_t)N * K / 1024, 256, 0, stream>>>((const float4*)W, (ushort4*)Wh);

    dim3 grid((M / 256) * (N / 256));
    gemm256_kernel<<<grid, 512, 0, stream>>>(Xb, Wh, Out, M, N, K);
}

// Round 12
// 284.465 us; speedup vs baseline: 1.1318x; 1.1234x over previous
//
#include <hip/hip_runtime.h>
#include <hip/hip_bf16.h>
#include <cstdint>

typedef __attribute__((ext_vector_type(4))) float f32x4;
typedef __attribute__((ext_vector_type(8))) short bf16x8;
typedef unsigned short u16;

__device__ inline u16 f2b(float f) {
    union { float f; uint32_t u; } c; c.f = f;
    uint32_t r = (c.u + 0x7FFFu + ((c.u >> 16) & 1u)) >> 16;
    return (u16)r;
}

// ---- Kernel 1: fused preprocessing ----
// Blocks [0, nwBlk): FWHT over one 1024-float block of W (float4-wide,
// h=1,2 in-register, h=4..512 via double-buffered LDS, 1 sync/stage), x1/32,
// emit bf16. Blocks [nwBlk, nwBlk+2048): grid-stride f32->bf16 cast of X.
// Both paths bench-verified separately (r8/r9); merged to co-schedule the
// streaming cast with the LDS-bound FWHT and save one launch.
__global__ void prep_kernel(const float4* __restrict__ W4, ushort4* __restrict__ Wh4, int nwBlk,
                            const float4* __restrict__ X, ushort4* __restrict__ Xb, int n4) {
    if ((int)blockIdx.x < nwBlk) {
        __shared__ float4 s4[2][256];
        const int tid = threadIdx.x;
        const size_t base = (size_t)blockIdx.x * 256;
        float4 v = W4[base + tid];
        v = float4{v.x + v.y, v.x - v.y, v.z + v.w, v.z - v.w};   // h=1
        v = float4{v.x + v.z, v.y + v.w, v.x - v.z, v.y - v.w};   // h=2
        int cur = 0;
        s4[0][tid] = v;
        __syncthreads();
#pragma unroll
        for (int h4 = 1; h4 < 256; h4 <<= 1) {
            float4 a = s4[cur][tid];
            float4 b = s4[cur][tid ^ h4];
            float4 r;
            if (tid & h4) r = float4{b.x - a.x, b.y - a.y, b.z - a.z, b.w - a.w};
            else          r = float4{a.x + b.x, a.y + b.y, a.z + b.z, a.w + b.w};
            cur ^= 1;
            s4[cur][tid] = r;
            __syncthreads();
            v = r;
        }
        ushort4 o;
        o.x = f2b(v.x * 0.03125f); o.y = f2b(v.y * 0.03125f);
        o.z = f2b(v.z * 0.03125f); o.w = f2b(v.w * 0.03125f);
        Wh4[base + tid] = o;
    } else {
        int i = (blockIdx.x - nwBlk) * blockDim.x + threadIdx.x;
        int stride = 2048 * blockDim.x;
        for (; i < n4; i += stride) {
            float4 v = X[i];
            ushort4 o;
            o.x = f2b(v.x); o.y = f2b(v.y); o.z = f2b(v.z); o.w = f2b(v.w);
            Xb[i] = o;
        }
    }
}

// ---- Kernel 3: 256x256-tile 8-wave pipelined bf16 GEMM, C = A * B^T ----
// EXACT r7/r9-verified kernel (236us GEMM, MfmaUtil 55%, 0 conflicts, 0 spill).
// Depth-2 read-ahead schedule; race audit in r7 notes. Post-r11 conclusion:
// 32x32x16 shape (r10/r11) and x2 unroll (r8) both regress; this 16x16x32
// depth-2 structure is the plateau of this design.
#define MFMA16(a, b, c) __builtin_amdgcn_mfma_f32_16x16x32_bf16(a, b, c, 0, 0, 0)

__global__ __launch_bounds__(512, 2) void gemm256_kernel(
    const u16* __restrict__ A, const u16* __restrict__ B, float* __restrict__ C,
    int M, int N, int K)
{
    __shared__ u16 lds[2][2][2][8192];   // [buf][op A=0/B=1][half][128*64]

    const int tid  = threadIdx.x;
    const int wid  = tid >> 6;
    const int lane = tid & 63;
    const int wr   = wid >> 2;           // 0..1
    const int wc   = wid & 3;            // 0..3

    const int ntn = N / 256;
    const int nwg = (M / 256) * ntn;
    int bid = blockIdx.x;
    int swz = (nwg % 8 == 0) ? ((bid & 7) * (nwg >> 3) + (bid >> 3)) : bid;
    const int tm = swz / ntn, tn = swz % ntn;
    const size_t rowA0 = (size_t)tm * 256;
    const size_t rowB0 = (size_t)tn * 256;
    const int TSTEPS = K / 64;

    const int stg_row  = wid * 8 + (lane >> 3);
    const int stg_slot = (lane & 7) ^ (stg_row & 7);   // pre-swizzled source slot

    const int frow = (lane & 15) * 64;
    const int fs0  = (((lane >> 4)) ^ (lane & 7)) * 8;       // ks=0 swizzled slot
    const int fs1  = ((4 + (lane >> 4)) ^ (lane & 7)) * 8;   // ks=1 swizzled slot

    auto stage = [&](const u16* __restrict__ G, size_t rowbase, u16* ldsHalf, int chunk, int t) {
        int teff = t < TSTEPS ? t : TSTEPS - 1;
        const u16* g = G + (rowbase + (size_t)(chunk * 64 + stg_row)) * (size_t)K
                         + teff * 64 + stg_slot * 8;
        u16* l = ldsHalf + chunk * 4096 + wid * 512;   // wave-uniform base; HW adds lane*16B
        __builtin_amdgcn_global_load_lds((const __attribute__((address_space(1))) void*)g,
                                         (__attribute__((address_space(3))) void*)l, 16, 0, 0);
    };

    f32x4 acc[8][4];
#pragma unroll
    for (int i = 0; i < 8; ++i)
#pragma unroll
        for (int j = 0; j < 4; ++j) acc[i][j] = (f32x4)(0.0f);

    // ---- prologue ----
    stage(B, rowB0,       &lds[0][1][0][0], 0, 0);   // B0(0)
    stage(B, rowB0,       &lds[0][1][0][0], 1, 0);
    stage(A, rowA0,       &lds[0][0][0][0], 0, 0);   // A(0)
    stage(A, rowA0,       &lds[0][0][0][0], 1, 0);
    stage(A, rowA0 + 128, &lds[0][0][1][0], 0, 0);
    stage(A, rowA0 + 128, &lds[0][0][1][0], 1, 0);
    stage(B, rowB0 + 128, &lds[0][1][1][0], 0, 0);   // B1(0)
    stage(B, rowB0 + 128, &lds[0][1][1][0], 1, 0);
    stage(B, rowB0,       &lds[1][1][0][0], 0, 1);   // B0(1)
    stage(B, rowB0,       &lds[1][1][0][0], 1, 1);
    asm volatile("s_waitcnt vmcnt(2)" ::: "memory");  // ALL of tile0 landed (incl. B1(0))
    __builtin_amdgcn_s_barrier();
    stage(A, rowA0,       &lds[1][0][0][0], 0, 1);   // A(1)
    stage(A, rowA0,       &lds[1][0][0][0], 1, 1);
    stage(A, rowA0 + 128, &lds[1][0][1][0], 0, 1);
    stage(A, rowA0 + 128, &lds[1][0][1][0], 1, 1);
    // vmem FIFO entering loop: [B0(1) 2][A(1) 4] = 6 outstanding.

    bf16x8 a0[4], b0[4], a1[4], cF[4], dF[4], eF[4];
    {
        const u16* Ahalf = &lds[0][0][wr][0];
        const u16* Bbase = &lds[0][1][wc >> 1][(wc & 1) * 4096];
#pragma unroll
        for (int i = 0; i < 4; ++i) a0[i] = *(const bf16x8*)&Ahalf[i * 1024 + frow + fs0];
#pragma unroll
        for (int j = 0; j < 4; ++j) b0[j] = *(const bf16x8*)&Bbase[j * 1024 + frow + fs0];
#pragma unroll
        for (int i = 0; i < 4; ++i) a1[i] = *(const bf16x8*)&Ahalf[(4 + i) * 1024 + frow + fs0];
    }

    for (int t = 0; t < TSTEPS; ++t) {
        const int cb = t & 1, nb = cb ^ 1;
        const u16* Ahalf  = &lds[cb][0][wr][0];
        const u16* Bbase  = &lds[cb][1][wc >> 1][(wc & 1) * 4096];
        const u16* AhalfN = &lds[nb][0][wr][0];
        const u16* BbaseN = &lds[nb][1][wc >> 1][(wc & 1) * 4096];

        // ===== P0: stage B1(t+1)->nb; issue F2(t); lgkm(8) [F0 done]; Q0 =====
        stage(B, rowB0 + 128, &lds[nb][1][1][0], 0, t + 1);
        stage(B, rowB0 + 128, &lds[nb][1][1][0], 1, t + 1);
#pragma unroll
        for (int i = 0; i < 4; ++i) cF[i] = *(const bf16x8*)&Ahalf[i * 1024 + frow + fs1];
#pragma unroll
        for (int j = 0; j < 4; ++j) dF[j] = *(const bf16x8*)&Bbase[j * 1024 + frow + fs1];
        asm volatile("s_waitcnt lgkmcnt(8)" ::: "memory");
        __builtin_amdgcn_sched_barrier(0);
        __builtin_amdgcn_s_setprio(1);
#pragma unroll
        for (int i = 0; i < 4; ++i)
#pragma unroll
            for (int j = 0; j < 4; ++j)
                acc[i][j] = MFMA16(a0[i], b0[j], acc[i][j]);
        __builtin_amdgcn_s_setprio(0);

        // ===== P1: issue F3(t); lgkm(12) pacing [F1 already done]; Q1 =====
#pragma unroll
        for (int i = 0; i < 4; ++i) eF[i] = *(const bf16x8*)&Ahalf[(4 + i) * 1024 + frow + fs1];
        asm volatile("s_waitcnt lgkmcnt(12)" ::: "memory");
        __builtin_amdgcn_sched_barrier(0);
        __builtin_amdgcn_s_setprio(1);
#pragma unroll
        for (int i = 0; i < 4; ++i)
#pragma unroll
            for (int j = 0; j < 4; ++j)
                acc[4 + i][j] = MFMA16(a1[i], b0[j], acc[4 + i][j]);
        __builtin_amdgcn_s_setprio(0);

        // ===== P2: lgkm(4) [F2 done]; vmcnt(2) [B0,A(t+1) landed]; bar;
        //          stage B0(t+2)->cb; issue F1(t+1); Q2 =====
        asm volatile("s_waitcnt lgkmcnt(4)" ::: "memory");
        asm volatile("s_waitcnt vmcnt(2)" ::: "memory");
        __builtin_amdgcn_sched_barrier(0);
        __builtin_amdgcn_s_barrier();
        stage(B, rowB0, &lds[cb][1][0][0], 0, t + 2);
        stage(B, rowB0, &lds[cb][1][0][0], 1, t + 2);
#pragma unroll
        for (int i = 0; i < 4; ++i) a1[i] = *(const bf16x8*)&AhalfN[(4 + i) * 1024 + frow + fs0];
        __builtin_amdgcn_s_setprio(1);
#pragma unroll
        for (int i = 0; i < 4; ++i)
#pragma unroll
            for (int j = 0; j < 4; ++j)
                acc[i][j] = MFMA16(cF[i], dF[j], acc[i][j]);
        __builtin_amdgcn_s_setprio(0);

        // ===== P3: lgkm(4) [F3 done]; vmcnt(2) [B1(t+1) landed]; bar;
        //          stage A(t+2)->cb; issue F0(t+1); Q3 =====
        asm volatile("s_waitcnt lgkmcnt(4)" ::: "memory");
        asm volatile("s_waitcnt vmcnt(2)" ::: "memory");
        __builtin_amdgcn_sched_barrier(0);
        __builtin_amdgcn_s_barrier();
        stage(A, rowA0,       &lds[cb][0][0][0], 0, t + 2);
        stage(A, rowA0,       &lds[cb][0][0][0], 1, t + 2);
        stage(A, rowA0 + 128, &lds[cb][0][1][0], 0, t + 2);
        stage(A, rowA0 + 128, &lds[cb][0][1][0], 1, t + 2);
#pragma unroll
        for (int i = 0; i < 4; ++i) a0[i] = *(const bf16x8*)&AhalfN[i * 1024 + frow + fs0];
#pragma unroll
        for (int j = 0; j < 4; ++j) b0[j] = *(const bf16x8*)&BbaseN[j * 1024 + frow + fs0];
        __builtin_amdgcn_s_setprio(1);
#pragma unroll
        for (int i = 0; i < 4; ++i)
#pragma unroll
            for (int j = 0; j < 4; ++j)
                acc[4 + i][j] = MFMA16(eF[i], dF[j], acc[4 + i][j]);
        __builtin_amdgcn_s_setprio(0);
    }

    // ---- epilogue: C/D layout col = lane&15, row = (lane>>4)*4 + reg ----
#pragma unroll
    for (int mf = 0; mf < 8; ++mf) {
        size_t row = rowA0 + wr * 128 + mf * 16 + (lane >> 4) * 4;
#pragma unroll
        for (int nf = 0; nf < 4; ++nf) {
            size_t col = rowB0 + wc * 64 + nf * 16 + (lane & 15);
            f32x4 v = acc[mf][nf];
#pragma unroll
            for (int j = 0; j < 4; ++j)
                C[(row + j) * (size_t)N + col] = v[j];
        }
    }
}

extern "C" void kernel_launch(void* const* d_in, const int* in_sizes, int n_in,
                              void* d_out, int out_size, void* d_ws, size_t ws_size,
                              hipStream_t stream) {
    const float* X = (const float*)d_in[0];   // (4,2048,4096) f32
    const float* W = (const float*)d_in[1];   // (4096,4096) f32
    float* Out = (float*)d_out;               // (4,2048,4096) f32

    const int K = 4096;
    const int N = in_sizes[1] / K;            // 4096
    const int M = in_sizes[0] / K;            // 8192

    u16* Xb = (u16*)d_ws;                     // M*K bf16 (64 MB)
    u16* Wh = (u16*)d_ws + (size_t)M * K;     // N*K bf16 (32 MB)

    const int nwBlk = (N * K) / 1024;         // 16384 FWHT blocks
    prep_kernel<<<nwBlk + 2048, 256, 0, stream>>>(
        (const float4*)W, (ushort4*)Wh, nwBlk,
        (const float4*)X, (ushort4*)Xb, (M * K) / 4);

    dim3 grid((M / 256) * (N / 256));
    gemm256_kernel<<<grid, 512, 0, stream>>>(Xb, Wh, Out, M, N, K);
}

// Round 13
// 280.333 us; speedup vs baseline: 1.1485x; 1.0147x over previous
//
#include <hip/hip_runtime.h>
#include <hip/hip_bf16.h>
#include <cstdint>

typedef __attribute__((ext_vector_type(4))) float f32x4;
typedef __attribute__((ext_vector_type(8))) short bf16x8;
typedef unsigned short u16;

__device__ inline u16 f2b(float f) {
    union { float f; uint32_t u; } c; c.f = f;
    uint32_t r = (c.u + 0x7FFFu + ((c.u >> 16) & 1u)) >> 16;
    return (u16)r;
}

// ---- Kernel 1: fused preprocessing (r12-verified, ~47us ~ BW floor) ----
// Blocks [0, nwBlk): FWHT over one 1024-float block of W (float4-wide,
// h=1,2 in-register, h=4..512 via double-buffered LDS, 1 sync/stage), x1/32,
// emit bf16. Blocks [nwBlk, nwBlk+2048): grid-stride f32->bf16 cast of X.
__global__ void prep_kernel(const float4* __restrict__ W4, ushort4* __restrict__ Wh4, int nwBlk,
                            const float4* __restrict__ X, ushort4* __restrict__ Xb, int n4) {
    if ((int)blockIdx.x < nwBlk) {
        __shared__ float4 s4[2][256];
        const int tid = threadIdx.x;
        const size_t base = (size_t)blockIdx.x * 256;
        float4 v = W4[base + tid];
        v = float4{v.x + v.y, v.x - v.y, v.z + v.w, v.z - v.w};   // h=1
        v = float4{v.x + v.z, v.y + v.w, v.x - v.z, v.y - v.w};   // h=2
        int cur = 0;
        s4[0][tid] = v;
        __syncthreads();
#pragma unroll
        for (int h4 = 1; h4 < 256; h4 <<= 1) {
            float4 a = s4[cur][tid];
            float4 b = s4[cur][tid ^ h4];
            float4 r;
            if (tid & h4) r = float4{b.x - a.x, b.y - a.y, b.z - a.z, b.w - a.w};
            else          r = float4{a.x + b.x, a.y + b.y, a.z + b.z, a.w + b.w};
            cur ^= 1;
            s4[cur][tid] = r;
            __syncthreads();
            v = r;
        }
        ushort4 o;
        o.x = f2b(v.x * 0.03125f); o.y = f2b(v.y * 0.03125f);
        o.z = f2b(v.z * 0.03125f); o.w = f2b(v.w * 0.03125f);
        Wh4[base + tid] = o;
    } else {
        int i = (blockIdx.x - nwBlk) * blockDim.x + threadIdx.x;
        int stride = 2048 * blockDim.x;
        for (; i < n4; i += stride) {
            float4 v = X[i];
            ushort4 o;
            o.x = f2b(v.x); o.y = f2b(v.y); o.z = f2b(v.z); o.w = f2b(v.w);
            Xb[i] = o;
        }
    }
}

// ---- Kernel 3: 256x256-tile 8-wave pipelined bf16 GEMM, C = A * B^T ----
// EXACT r5-verified kernel — the session-best GEMM variant (231.4-232.6us
// across all r5 profiled dispatches vs 235.7-239.3 for the r7 depth-2
// variant; VGPR 112, 0 conflicts, 0 spill, absmax 0.0625).
// Even read spread 8/4/4/8 per phase with cross-tile prefetch of next tile's
// (a0,b0) fragments at ph3 (issued after vmcnt(2)+barrier confirms tile t+1
// landed). Counted lgkm waits from explicit per-wave FIFO trace:
//   ph0: issue a1,b1(8)  lgkm(8)  -> a0,b0 done   Q0 = a0*b0  -> acc[0..3]
//   ph1: issue a2(4)     lgkm(8)  -> a1 done      Q1 = a1*b0  -> acc[4..7]
//   ph2: bar; stage B0(t+2); issue a3(4); lgkm(4) -> a2,b1    Q2 = a2*b1 -> acc[0..3]
//   ph3: lgkm(0); vmcnt(2); bar; stage A(t+2); issue a0,b0(t+1); Q3 = a3*b1 -> acc[4..7]
// vmem FIFO at ph3: [B0(t+1)2][A(t+1)4][B1(t+1)2][B0(t+2)2]=10, vmcnt(2) =>
// all of t+1 landed, B0(t+2) stays in flight (never drain to 0 mid-loop).
// Staging: ph0 B1(t+1)->nb, ph2 B0(t+2)->cb, ph3 A(t+2)->cb (WAR fenced by the
// barrier after each region's last reads completed at a counted wait).
// LDS 16B-slot XOR swizzle (slot^=row&7), bank-conflict-free per r2 PMC.
#define MFMA16(a, b, c) __builtin_amdgcn_mfma_f32_16x16x32_bf16(a, b, c, 0, 0, 0)

__global__ __launch_bounds__(512, 2) void gemm256_kernel(
    const u16* __restrict__ A, const u16* __restrict__ B, float* __restrict__ C,
    int M, int N, int K)
{
    __shared__ u16 lds[2][2][2][8192];   // [buf][op A=0/B=1][half][128*64]

    const int tid  = threadIdx.x;
    const int wid  = tid >> 6;
    const int lane = tid & 63;
    const int wr   = wid >> 2;           // 0..1
    const int wc   = wid & 3;            // 0..3

    const int ntn = N / 256;
    const int nwg = (M / 256) * ntn;
    int bid = blockIdx.x;
    int swz = (nwg % 8 == 0) ? ((bid & 7) * (nwg >> 3) + (bid >> 3)) : bid;
    const int tm = swz / ntn, tn = swz % ntn;
    const size_t rowA0 = (size_t)tm * 256;
    const size_t rowB0 = (size_t)tn * 256;
    const int TSTEPS = K / 64;

    // staging constants: wave w covers rows chunk*64 + w*8 .. +8 of a half-tile
    const int stg_row  = wid * 8 + (lane >> 3);
    const int stg_slot = (lane & 7) ^ (stg_row & 7);   // pre-swizzled source slot

    // read-side constants
    const int frow = (lane & 15) * 64;
    const int fs0  = (((lane >> 4)) ^ (lane & 7)) * 8;       // ks=0 swizzled slot
    const int fs1  = ((4 + (lane >> 4)) ^ (lane & 7)) * 8;   // ks=1 swizzled slot

    auto stage = [&](const u16* __restrict__ G, size_t rowbase, u16* ldsHalf, int chunk, int t) {
        int teff = t < TSTEPS ? t : TSTEPS - 1;
        const u16* g = G + (rowbase + (size_t)(chunk * 64 + stg_row)) * (size_t)K
                         + teff * 64 + stg_slot * 8;
        u16* l = ldsHalf + chunk * 4096 + wid * 512;   // wave-uniform base; HW adds lane*16B
        __builtin_amdgcn_global_load_lds((const __attribute__((address_space(1))) void*)g,
                                         (__attribute__((address_space(3))) void*)l, 16, 0, 0);
    };

    f32x4 acc[8][4];
#pragma unroll
    for (int i = 0; i < 8; ++i)
#pragma unroll
        for (int j = 0; j < 4; ++j) acc[i][j] = (f32x4)(0.0f);

    // ---- prologue ----
    // vmem FIFO after prologue: [B0(1) 2][A(1) 4] = 6 outstanding (steady state).
    stage(B, rowB0,       &lds[0][1][0][0], 0, 0);   // B0(0)
    stage(B, rowB0,       &lds[0][1][0][0], 1, 0);
    stage(A, rowA0,       &lds[0][0][0][0], 0, 0);   // A(0)
    stage(A, rowA0,       &lds[0][0][0][0], 1, 0);
    stage(A, rowA0 + 128, &lds[0][0][1][0], 0, 0);
    stage(A, rowA0 + 128, &lds[0][0][1][0], 1, 0);
    stage(B, rowB0 + 128, &lds[0][1][1][0], 0, 0);   // B1(0)
    stage(B, rowB0 + 128, &lds[0][1][1][0], 1, 0);
    stage(B, rowB0,       &lds[1][1][0][0], 0, 1);   // B0(1)
    stage(B, rowB0,       &lds[1][1][0][0], 1, 1);
    asm volatile("s_waitcnt vmcnt(2)" ::: "memory");  // tile0 landed; B0(1) in flight
    __builtin_amdgcn_s_barrier();
    stage(A, rowA0,       &lds[1][0][0][0], 0, 1);   // A(1)
    stage(A, rowA0,       &lds[1][0][0][0], 1, 1);
    stage(A, rowA0 + 128, &lds[1][0][1][0], 0, 1);
    stage(A, rowA0 + 128, &lds[1][0][1][0], 1, 1);

    bf16x8 a0[4], b0v[4];
    {
        const u16* Ahalf = &lds[0][0][wr][0];
        const u16* Bbase = &lds[0][1][wc >> 1][(wc & 1) * 4096];
#pragma unroll
        for (int i = 0; i < 4; ++i) a0[i]  = *(const bf16x8*)&Ahalf[i * 1024 + frow + fs0];
#pragma unroll
        for (int j = 0; j < 4; ++j) b0v[j] = *(const bf16x8*)&Bbase[j * 1024 + frow + fs0];
    }

    for (int t = 0; t < TSTEPS; ++t) {
        const int cb = t & 1, nb = cb ^ 1;
        const u16* Ahalf  = &lds[cb][0][wr][0];
        const u16* Bbase  = &lds[cb][1][wc >> 1][(wc & 1) * 4096];
        const u16* AhalfN = &lds[nb][0][wr][0];
        const u16* BbaseN = &lds[nb][1][wc >> 1][(wc & 1) * 4096];

        bf16x8 a1[4], bb1[4], a2[4], a3[4];

        // ===== phase 0: issue a1(4)+b1(4); stage B1(t+1)->nb; lgkm(8); Q0 =====
#pragma unroll
        for (int i = 0; i < 4; ++i) a1[i]  = *(const bf16x8*)&Ahalf[(4 + i) * 1024 + frow + fs0];
#pragma unroll
        for (int j = 0; j < 4; ++j) bb1[j] = *(const bf16x8*)&Bbase[j * 1024 + frow + fs1];
        stage(B, rowB0 + 128, &lds[nb][1][1][0], 0, t + 1);
        stage(B, rowB0 + 128, &lds[nb][1][1][0], 1, t + 1);
        asm volatile("s_waitcnt lgkmcnt(8)" ::: "memory");    // a0,b0 done
        __builtin_amdgcn_sched_barrier(0);
        __builtin_amdgcn_s_setprio(1);
#pragma unroll
        for (int i = 0; i < 4; ++i)
#pragma unroll
            for (int j = 0; j < 4; ++j)
                acc[i][j] = MFMA16(a0[i], b0v[j], acc[i][j]);
        __builtin_amdgcn_s_setprio(0);

        // ===== phase 1: issue a2(4); lgkm(8); Q1 =====
#pragma unroll
        for (int i = 0; i < 4; ++i) a2[i] = *(const bf16x8*)&Ahalf[i * 1024 + frow + fs1];
        asm volatile("s_waitcnt lgkmcnt(8)" ::: "memory");    // a1 done
        __builtin_amdgcn_sched_barrier(0);
        __builtin_amdgcn_s_setprio(1);
#pragma unroll
        for (int i = 0; i < 4; ++i)
#pragma unroll
            for (int j = 0; j < 4; ++j)
                acc[4 + i][j] = MFMA16(a1[i], b0v[j], acc[4 + i][j]);
        __builtin_amdgcn_s_setprio(0);

        // ===== phase 2: bar (B0 WAR fence); stage B0(t+2)->cb; issue a3(4); lgkm(4); Q2 =====
        __builtin_amdgcn_s_barrier();
        stage(B, rowB0, &lds[cb][1][0][0], 0, t + 2);
        stage(B, rowB0, &lds[cb][1][0][0], 1, t + 2);
#pragma unroll
        for (int i = 0; i < 4; ++i) a3[i] = *(const bf16x8*)&Ahalf[(4 + i) * 1024 + frow + fs1];
        asm volatile("s_waitcnt lgkmcnt(4)" ::: "memory");    // bb1, a2 done
        __builtin_amdgcn_sched_barrier(0);
        __builtin_amdgcn_s_setprio(1);
#pragma unroll
        for (int i = 0; i < 4; ++i)
#pragma unroll
            for (int j = 0; j < 4; ++j)
                acc[i][j] = MFMA16(a2[i], bb1[j], acc[i][j]);
        __builtin_amdgcn_s_setprio(0);

        // ===== phase 3: lgkm(0)+vmcnt(2); bar; stage A(t+2)->cb; prefetch a0,b0(t+1); Q3 =====
        asm volatile("s_waitcnt lgkmcnt(0)" ::: "memory");    // a3 done (A WAR fence ready)
        asm volatile("s_waitcnt vmcnt(2)" ::: "memory");      // all of tile t+1 landed
        __builtin_amdgcn_sched_barrier(0);
        __builtin_amdgcn_s_barrier();
        stage(A, rowA0,       &lds[cb][0][0][0], 0, t + 2);
        stage(A, rowA0,       &lds[cb][0][0][0], 1, t + 2);
        stage(A, rowA0 + 128, &lds[cb][0][1][0], 0, t + 2);
        stage(A, rowA0 + 128, &lds[cb][0][1][0], 1, t + 2);
#pragma unroll
        for (int i = 0; i < 4; ++i) a0[i]  = *(const bf16x8*)&AhalfN[i * 1024 + frow + fs0];
#pragma unroll
        for (int j = 0; j < 4; ++j) b0v[j] = *(const bf16x8*)&BbaseN[j * 1024 + frow + fs0];
        __builtin_amdgcn_s_setprio(1);
#pragma unroll
        for (int i = 0; i < 4; ++i)
#pragma unroll
            for (int j = 0; j < 4; ++j)
                acc[4 + i][j] = MFMA16(a3[i], bb1[j], acc[4 + i][j]);
        __builtin_amdgcn_s_setprio(0);
    }

    // ---- epilogue: C/D layout col = lane&15, row = (lane>>4)*4 + reg ----
#pragma unroll
    for (int mf = 0; mf < 8; ++mf) {
        size_t row = rowA0 + wr * 128 + mf * 16 + (lane >> 4) * 4;
#pragma unroll
        for (int nf = 0; nf < 4; ++nf) {
            size_t col = rowB0 + wc * 64 + nf * 16 + (lane & 15);
            f32x4 v = acc[mf][nf];
#pragma unroll
            for (int j = 0; j < 4; ++j)
                C[(row + j) * (size_t)N + col] = v[j];
        }
    }
}

extern "C" void kernel_launch(void* const* d_in, const int* in_sizes, int n_in,
                              void* d_out, int out_size, void* d_ws, size_t ws_size,
                              hipStream_t stream) {
    const float* X = (const float*)d_in[0];   // (4,2048,4096) f32
    const float* W = (const float*)d_in[1];   // (4096,4096) f32
    float* Out = (float*)d_out;               // (4,2048,4096) f32

    const int K = 4096;
    const int N = in_sizes[1] / K;            // 4096
    const int M = in_sizes[0] / K;            // 8192

    u16* Xb = (u16*)d_ws;                     // M*K bf16 (64 MB)
    u16* Wh = (u16*)d_ws + (size_t)M * K;     // N*K bf16 (32 MB)

    const int nwBlk = (N * K) / 1024;         // 16384 FWHT blocks
    prep_kernel<<<nwBlk + 2048, 256, 0, stream>>>(
        (const float4*)W, (ushort4*)Wh, nwBlk,
        (const float4*)X, (ushort4*)Xb, (M * K) / 4);

    dim3 grid((M / 256) * (N / 256));
    gemm256_kernel<<<grid, 512, 0, stream>>>(Xb, Wh, Out, M, N, K);
}